// Round 4
// baseline (607.100 us; speedup 1.0000x reference)
//
#include <hip/hip_runtime.h>

#define S_LEN 2048
#define NL 51
#define LS 53
#define ST 51
#define EN 52
#define NBATCH 256
#define CH 128                 // steps per chunk
#define CHF (CH * NL)          // 6528 floats per chunk
#define BUF_ROWS (CH + 1)      // 129: extra row kills the boundary lookahead case
#define BUF_F (BUF_ROWS * NL)  // 6579
#define TOTF (S_LEN * NL)      // 104448
#define L2E 1.4426950408889634f
#define LN2 0.6931471805599453f

typedef float f32x4 __attribute__((ext_vector_type(4)));

__device__ __forceinline__ float rlane(float v, int l) {
    return __builtin_bit_cast(float, __builtin_amdgcn_readlane(__builtin_bit_cast(int, v), l));
}

// wave-1 producer: copy logit chunk ck (129 rows, clamped to array end) into LDS
__device__ __forceinline__ void stage_chunk(const float* __restrict__ lg, float* dst,
                                            int ck, int lid) {
    const float* src = lg + (long)ck * CHF;
    int nf = TOTF - ck * CHF;
    nf = (nf < BUF_F) ? nf : BUF_F;
    const int nf4 = nf >> 2;
    const f32x4* s4 = (const f32x4*)src;   // 16B aligned: ck*26112 % 16 == 0
    f32x4* d4 = (f32x4*)dst;
    for (int i = lid; i < nf4; i += 64) d4[i] = s4[i];
    for (int i = (nf4 << 2) + lid; i < nf; i += 64) dst[i] = src[i];
}

// One block per batch element, 2 waves.
// Wave 0: forward recursion in the multiplicative domain, lagged divisor
// (identical math to R2/R3 which passed): e_{t+1} = s_t*q_t, s_t = E e_t,
// q_t = gexp_t * rcp(ssum_{t-1}), ssum = s[START] (row START of E all-ones),
// applied divisors' log2 accumulated in off2. E-row in 14 named f32x4 VGPRs;
// e broadcast via LDS (ds_write_b32 + 14 ds_read_b128, same-wave DS order).
// Logit feed comes from LDS (single ds_read_b32/step, off the e-chain) —
// NO global loads in the scan wave.
// Wave 1: double-buffers logit chunks global->LDS + computes gold slices.
__global__ __launch_bounds__(128, 1) void crf_kernel(
    const float* __restrict__ logits,   // [256, 2048, 51]
    const int*   __restrict__ labels,   // [256, 2048]
    const int*   __restrict__ lens,     // [256]
    const float* __restrict__ Tr,       // [53, 53]  (to, from)
    float*       __restrict__ out)      // [256]
{
    const int b   = blockIdx.x;
    const int tid = threadIdx.x;
    const int wv  = tid >> 6;
    const int lid = tid & 63;
    const int len = lens[b];
    const int nch = (len + CH - 1) >> 7;

    const float* lg = logits + (long)b * TOTF;
    const int*   lb = labels + (long)b * S_LEN;

    __shared__ float sh_gold;
    __shared__ float sh_norm;
    __shared__ __align__(16) float sh_e[64];
    __shared__ __align__(16) float sh_lg[2][BUF_F];

    // ---- persistent per-wave state ----
    f32x4 er0, er1, er2, er3, er4, er5, er6, er7, er8, er9, er10, er11, er12, er13;
    float tmax = -1e30f, e = 0.f, q = 0.f, off2 = 0.f, lprev = 0.f;
    float p = 0.f;                       // gold accumulator (wave 1)
    const int j  = lid;
    const int jj = (j < NL) ? j : 0;     // safe LDS column for inactive lanes

    if (wv == 1) {
        stage_chunk(lg, sh_lg[0], 0, lid);
    } else {
        const float* trow = Tr + j * LS;
#define GT(K)    (((j < LS) && ((K) < LS)) ? trow[(K)] : -1e30f)
#define LD4(V,B) { V.x = GT(B); V.y = GT((B)+1); V.z = GT((B)+2); V.w = GT((B)+3); }
        LD4(er0, 0)  LD4(er1, 4)  LD4(er2, 8)   LD4(er3, 12)
        LD4(er4, 16) LD4(er5, 20) LD4(er6, 24)  LD4(er7, 28)
        LD4(er8, 32) LD4(er9, 36) LD4(er10, 40) LD4(er11, 44)
        LD4(er12, 48) LD4(er13, 52)
#undef GT
#undef LD4
#define MX4(V) tmax = fmaxf(tmax, fmaxf(fmaxf(V.x, V.y), fmaxf(V.z, V.w)));
        MX4(er0) MX4(er1) MX4(er2) MX4(er3) MX4(er4) MX4(er5) MX4(er6)
        MX4(er7) MX4(er8) MX4(er9) MX4(er10) MX4(er11) MX4(er12) MX4(er13)
#undef MX4
#define EX4(V) { V.x = __builtin_amdgcn_exp2f((V.x - tmax) * L2E); \
                 V.y = __builtin_amdgcn_exp2f((V.y - tmax) * L2E); \
                 V.z = __builtin_amdgcn_exp2f((V.z - tmax) * L2E); \
                 V.w = __builtin_amdgcn_exp2f((V.w - tmax) * L2E); }
        EX4(er0) EX4(er1) EX4(er2) EX4(er3) EX4(er4) EX4(er5) EX4(er6)
        EX4(er7) EX4(er8) EX4(er9) EX4(er10) EX4(er11) EX4(er12) EX4(er13)
#undef EX4
        e = (j == ST) ? 1.f : 0.f;       // exp(alpha0); lanes != START -> ~0
    }
    __syncthreads();                     // chunk 0 staged

    if (wv == 0) {                       // q_0 = gexp_0 (logit[0] from LDS)
        float nl0 = sh_lg[0][jj];
        nl0 = (j < NL) ? nl0 : -100.f;
        q = __builtin_amdgcn_exp2f((nl0 + tmax) * L2E);
    }

#define MATVEC(SOUT) { \
        sh_e[j] = e; \
        const f32x4* sp = (const f32x4*)sh_e; \
        f32x4 a0 = sp[0] * er0, a1 = sp[1] * er1, a2 = sp[2] * er2, a3 = sp[3] * er3; \
        a0 += sp[4]  * er4;  a1 += sp[5]  * er5;  a2 += sp[6]  * er6;  a3 += sp[7]  * er7; \
        a0 += sp[8]  * er8;  a1 += sp[9]  * er9;  a2 += sp[10] * er10; a3 += sp[11] * er11; \
        a0 += sp[12] * er12; a1 += sp[13] * er13; \
        f32x4 aa = (a0 + a1) + (a2 + a3); \
        SOUT = (aa.x + aa.y) + (aa.z + aa.w); }

    for (int c = 0; c < nch; ++c) {
        const int L = min(CH, len - c * CH);
        if (wv == 1) {
            if (c + 1 < nch) stage_chunk(lg, sh_lg[(c + 1) & 1], c + 1, lid);
            // gold slice for this chunk (latency-tolerant global gathers)
            const int t0 = c * CH;
            for (int t = t0 + lid; t < t0 + L; t += 64) {
                const int lab  = lb[t];
                const int prev = t ? lb[t - 1] : ST;
                p += lg[(long)t * NL + lab] + Tr[lab * LS + prev];
            }
        } else {
            const float* base = sh_lg[c & 1];
            int roff = NL;               // (tloc+1)*NL : next-step logit row
#pragma unroll 2
            for (int tloc = 0; tloc < L; ++tloc) {
                float nlr = base[roff + jj];          // ds_read_b32, off e-chain
                float nl  = (j < NL) ? nlr : -100.f;
                float s; MATVEC(s);
                e = s * q;
                float ssum = rlane(s, ST);
                off2 += lprev;
                lprev = __builtin_amdgcn_logf(ssum);  // v_log_f32 = log2
                q = __builtin_amdgcn_exp2f((nl + tmax) * L2E) * __builtin_amdgcn_rcpf(ssum);
                roff += NL;
            }
        }
        __syncthreads();                 // buffer handoff
    }

    if (wv == 0) {
        // norm = logsumexp_j(alpha[j] + T[END, j]) : one more matvec, row END
        float s; MATVEC(s);
        float sEnd  = rlane(s, EN);
        float tmEnd = rlane(tmax, EN);
        if (j == 0)
            sh_norm = (off2 + __builtin_amdgcn_logf(sEnd)) * LN2 + tmEnd;
    } else {
        if (lid == 0) p += Tr[EN * LS + lb[len - 1]];   // final transition to END
#pragma unroll
        for (int off = 32; off > 0; off >>= 1)
            p += __shfl_down(p, off, 64);
        if (lid == 0) sh_gold = p;
    }
#undef MATVEC
    __syncthreads();
    if (tid == 0) out[b] = sh_gold - sh_norm;
}

extern "C" void kernel_launch(void* const* d_in, const int* in_sizes, int n_in,
                              void* d_out, int out_size, void* d_ws, size_t ws_size,
                              hipStream_t stream) {
    const float* logits = (const float*)d_in[0];
    const int*   labels = (const int*)d_in[1];
    const int*   lens   = (const int*)d_in[2];
    const float* Tr     = (const float*)d_in[3];
    float*       out    = (float*)d_out;
    crf_kernel<<<NBATCH, 128, 0, stream>>>(logits, labels, lens, Tr, out);
}